// Round 3
// baseline (331.497 us; speedup 1.0000x reference)
//
#include <hip/hip_runtime.h>
#include <hip/hip_bf16.h>
#include <math.h>

#define N_NODES 50000
#define N_EDGES 800000
#define HID 128
#define N_GRAPHS 128
#define OUTC 10
#define BN_EPS 1e-5f

#define SCAN_B 256
#define N_SCAN_BLOCKS ((N_NODES + SCAN_B - 1) / SCAN_B)  // 196

#define POOL_CHUNK 32
#define N_POOL_BLOCKS ((N_NODES + POOL_CHUNK - 1) / POOL_CHUNK)  // 1563

#define EPAD 8                // CSR row padding (edges), multiple of 8 for guard-free inner loop
#define E_SRC_CAP (N_EDGES + N_NODES * EPAD)  // worst-case padded edge slots

#define LDA 136               // LDS row stride (ushorts): 272 B = 17*16B -> aligned b128, 2-way banks

#define DEG_BLOCKS 400        // edge-processing blocks in deg kernel (block DEG_BLOCKS = W-pack)

typedef short short8 __attribute__((ext_vector_type(8)));
typedef float floatx4 __attribute__((ext_vector_type(4)));

template <typename T, typename F>
__device__ inline T bitcast(F f) {
    union { F a; T b; } u;
    u.a = f;
    return u.b;
}

__device__ inline unsigned short f2bf(float x) {
    return __hip_bfloat16_raw(__float2bfloat16(x)).x;
}

// ---------------- degree count via global atomics (L2-resident counters) + W-pack ----------
__global__ __launch_bounds__(1024) void deg_kernel(const int* __restrict__ src,
                                                   const int* __restrict__ dst,
                                                   int* __restrict__ cnt_out,
                                                   int* __restrict__ cnt_in,
                                                   const float* __restrict__ W1,
                                                   const float* __restrict__ W2,
                                                   unsigned short* __restrict__ Wp) {
    if (blockIdx.x == DEG_BLOCKS) {
        // pack W into MFMA B-frag order: lane holds B[k=quad*8+j][n=lane&15], j in [0,8)
        for (int q = threadIdx.x; q < 4096; q += 1024) {  // 2 mats x 32 tiles x 64 lanes
            int wi = q >> 11;
            const float* __restrict__ W = wi ? W2 : W1;
            int t2 = q & 2047;
            int tile = t2 >> 6, lane = t2 & 63;
            int kc = tile >> 3, nt = tile & 7;
            int n = lane & 15, quad = lane >> 4;
            unsigned short v[8];
#pragma unroll
            for (int j = 0; j < 8; j++) {
                int k = kc * 32 + quad * 8 + j;
                v[j] = f2bf(W[k * HID + nt * 16 + n]);
            }
            *(uint4*)&Wp[(size_t)q * 8] = *(uint4*)v;
        }
        return;
    }
    for (int e = blockIdx.x * 1024 + threadIdx.x; e < N_EDGES; e += DEG_BLOCKS * 1024) {
        atomicAdd(&cnt_out[src[e]], 1);
        atomicAdd(&cnt_in[dst[e]], 1);
    }
}

// ---------------- per-chunk padded in-degree sums (scan phase 1) ----------------
__global__ __launch_bounds__(SCAN_B) void bsum_kernel(const int* __restrict__ cnt_in,
                                                      int* __restrict__ bsum) {
    __shared__ int red[SCAN_B];
    int t = threadIdx.x;
    int i = blockIdx.x * SCAN_B + t;
    int c = (i < N_NODES) ? cnt_in[i] : 0;
    red[t] = (c + EPAD - 1) & ~(EPAD - 1);
    __syncthreads();
    for (int o = SCAN_B / 2; o > 0; o >>= 1) {
        if (t < o) red[t] += red[t + o];
        __syncthreads();
    }
    if (t == 0) bsum[blockIdx.x] = red[0];
}

// ---------------- scan (fused): per-block bsum scan + row_ptr/cursor/inv write + pad fill ----
__global__ void scan_write_kernel(const int* __restrict__ cnt_out,
                                  const int* __restrict__ cnt_in,
                                  const int* __restrict__ bsum,
                                  int* __restrict__ row_ptr, int* __restrict__ cursor,
                                  float* __restrict__ inv_out, float* __restrict__ inv_in,
                                  int* __restrict__ edge_src) {
    __shared__ int sb[SCAN_B];    // chunk-sum scan (redundant per block, kills a dispatch)
    __shared__ int part[SCAN_B];  // node scan
    int t = threadIdx.x;
    sb[t] = (t < N_SCAN_BLOCKS) ? bsum[t] : 0;
    __syncthreads();
    for (int off = 1; off < SCAN_B; off <<= 1) {
        int u = (t >= off) ? sb[t - off] : 0;
        __syncthreads();
        sb[t] += u;
        __syncthreads();
    }
    int boff = (blockIdx.x == 0) ? 0 : sb[blockIdx.x - 1];  // exclusive chunk offset

    int i = blockIdx.x * SCAN_B + t;
    int raw = (i < N_NODES) ? cnt_in[i] : 0;
    int v = (raw + EPAD - 1) & ~(EPAD - 1);
    part[t] = v;
    __syncthreads();
    for (int off = 1; off < SCAN_B; off <<= 1) {
        int u = (t >= off) ? part[t - off] : 0;
        __syncthreads();
        part[t] += u;
        __syncthreads();
    }
    if (i < N_NODES) {
        int ex = part[t] - v + boff;
        row_ptr[i] = ex;
        cursor[i] = ex;  // atomic fill cursor starts at row base
        inv_in[i] = rsqrtf(fmaxf((float)raw, 1.0f));
        inv_out[i] = rsqrtf(fmaxf((float)cnt_out[i], 1.0f));
        for (int p = ex + raw; p < ex + v; p++) edge_src[p] = N_NODES;  // pad slots
        if (i == N_NODES - 1) row_ptr[N_NODES] = ex + v;  // padded total
    }
}

// ---------------- CSR fill via global atomic cursors (pads disjoint) ----------------
__global__ __launch_bounds__(1024) void csr_fill_kernel(const int* __restrict__ src,
                                                        const int* __restrict__ dst,
                                                        int* __restrict__ cursor,
                                                        int* __restrict__ edge_src) {
    for (int e = blockIdx.x * 1024 + threadIdx.x; e < N_EDGES; e += DEG_BLOCKS * 1024) {
        int d = dst[e];
        int pos = atomicAdd(&cursor[d], 1);
        edge_src[pos] = src[e];
    }
}

// ================= MFMA matmul =================
__device__ inline void mm_tail(const unsigned short* __restrict__ xs,
                               const unsigned short* __restrict__ Wp,
                               __hip_bfloat16* __restrict__ Y, int row0) {
    int tid = threadIdx.x;
    int wave = tid >> 6, lane = tid & 63;
    int m = lane & 15, quad = lane >> 4;
    int rowl = wave * 16;

    short8 a[4];
#pragma unroll
    for (int kc = 0; kc < 4; kc++)
        a[kc] = bitcast<short8>(*(const uint4*)&xs[(rowl + m) * LDA + kc * 32 + quad * 8]);

    floatx4 acc[8];
#pragma unroll
    for (int nt = 0; nt < 8; nt++) acc[nt] = (floatx4){0.f, 0.f, 0.f, 0.f};

#pragma unroll
    for (int nt = 0; nt < 8; nt++) {
#pragma unroll
        for (int kc = 0; kc < 4; kc++) {
            short8 bfr = bitcast<short8>(
                *(const uint4*)&Wp[((size_t)(kc * 8 + nt) * 64 + lane) * 8]);
            acc[nt] = __builtin_amdgcn_mfma_f32_16x16x32_bf16(a[kc], bfr, acc[nt], 0, 0, 0);
        }
    }

    // C/D layout: col = lane&15, row = quad*4 + reg  [verified m89]
#pragma unroll
    for (int nt = 0; nt < 8; nt++) {
#pragma unroll
        for (int i = 0; i < 4; i++) {
            int rg = row0 + rowl + quad * 4 + i;
            if (rg < N_NODES + 1) {
                Y[(size_t)rg * HID + nt * 16 + m] = __float2bfloat16(acc[nt][i]);
            }
        }
    }
}

// fp32 input with row scale (layer 1)
__global__ __launch_bounds__(256) void matmul_kernel(const float* __restrict__ X,
                                                     const float* __restrict__ scale,
                                                     const unsigned short* __restrict__ Wp,
                                                     __hip_bfloat16* __restrict__ Y) {
    __shared__ unsigned short xs[64 * LDA];
    int tid = threadIdx.x;
    int row0 = blockIdx.x * 64;
    for (int j = 0; j < 8; j++) {
        int idx4 = j * 256 + tid;
        int r = idx4 >> 5;
        int col = (idx4 & 31) * 4;
        int rg = row0 + r;
        float4 v = make_float4(0.f, 0.f, 0.f, 0.f);
        if (rg < N_NODES) {
            v = *(const float4*)&X[(size_t)rg * HID + col];
            float sc = scale[rg];
            v.x *= sc; v.y *= sc; v.z *= sc; v.w *= sc;
        }
        unsigned short o[4];
        o[0] = f2bf(v.x); o[1] = f2bf(v.y); o[2] = f2bf(v.z); o[3] = f2bf(v.w);
        *(ushort4*)&xs[r * LDA + col] = *(ushort4*)o;
    }
    __syncthreads();
    mm_tail(xs, Wp, Y, row0);
}

// bf16 pre-scaled input (layer 2): staging is a straight vectorized copy
__global__ __launch_bounds__(256) void matmul_bf16_kernel(const __hip_bfloat16* __restrict__ Xb,
                                                          const unsigned short* __restrict__ Wp,
                                                          __hip_bfloat16* __restrict__ Y) {
    __shared__ unsigned short xs[64 * LDA];
    int tid = threadIdx.x;
    int row0 = blockIdx.x * 64;
    for (int j = 0; j < 4; j++) {
        int idx8 = j * 256 + tid;  // 8-bf16 chunks: 16 per row
        int r = idx8 >> 4;
        int c = (idx8 & 15) * 8;
        int rg = row0 + r;
        uint4 v = make_uint4(0u, 0u, 0u, 0u);
        if (rg < N_NODES) v = *(const uint4*)&Xb[(size_t)rg * HID + c];
        *(uint4*)&xs[r * LDA + c] = v;
    }
    __syncthreads();
    mm_tail(xs, Wp, Y, row0);
}

// ================= CSR gather-accumulate =================
// BF16OUT: store bf16(inv_out[n] * relu(acc*inv_in + b)) — pre-scaled for next matmul.
// else:    store fp32 relu(acc*inv_in + b) for pooling.
template <bool BF16OUT>
__global__ __launch_bounds__(256) void agg_kernel_t(const __hip_bfloat16* __restrict__ Y,
                                                    const int* __restrict__ edge_src,
                                                    const int* __restrict__ row_ptr,
                                                    const float* __restrict__ inv_in,
                                                    const float* __restrict__ inv_out,
                                                    const float* __restrict__ bias,
                                                    void* __restrict__ Xout) {
    const uint4* __restrict__ Yq = (const uint4*)Y;  // 8 bf16 per uint4
    int wave = threadIdx.x >> 6;
    int lane = threadIdx.x & 63;
    int n = blockIdx.x * 4 + wave;
    if (n >= N_NODES) return;
    int beg = row_ptr[n], end = row_ptr[n + 1];  // length multiple of 8
    int esub = lane >> 4;   // which of 4 concurrent edges
    int f16  = lane & 15;   // feature quad: feats f16*8 .. f16*8+7
    float acc[8] = {};
    for (int base = beg; base < end; base += 64) {
        int mm = min(64, end - base);  // multiple of 8
        int idx = (lane < mm) ? edge_src[base + lane] : N_NODES;
        for (int j = 0; j < mm; j += 8) {
            int s0 = __shfl(idx, j + esub);
            int s1 = __shfl(idx, j + 4 + esub);
            uint4 u0 = Yq[s0 * (HID / 8) + f16];
            uint4 u1 = Yq[s1 * (HID / 8) + f16];
            acc[0] += __uint_as_float(u0.x << 16); acc[1] += __uint_as_float(u0.x & 0xFFFF0000u);
            acc[2] += __uint_as_float(u0.y << 16); acc[3] += __uint_as_float(u0.y & 0xFFFF0000u);
            acc[4] += __uint_as_float(u0.z << 16); acc[5] += __uint_as_float(u0.z & 0xFFFF0000u);
            acc[6] += __uint_as_float(u0.w << 16); acc[7] += __uint_as_float(u0.w & 0xFFFF0000u);
            acc[0] += __uint_as_float(u1.x << 16); acc[1] += __uint_as_float(u1.x & 0xFFFF0000u);
            acc[2] += __uint_as_float(u1.y << 16); acc[3] += __uint_as_float(u1.y & 0xFFFF0000u);
            acc[4] += __uint_as_float(u1.z << 16); acc[5] += __uint_as_float(u1.z & 0xFFFF0000u);
            acc[6] += __uint_as_float(u1.w << 16); acc[7] += __uint_as_float(u1.w & 0xFFFF0000u);
        }
    }
#pragma unroll
    for (int i = 0; i < 8; i++) {
        acc[i] += __shfl_xor(acc[i], 16);
        acc[i] += __shfl_xor(acc[i], 32);
    }
    if (lane < 16) {
        float si = inv_in[n];
        int f0 = f16 * 8;
        float4 b0 = *(const float4*)&bias[f0];
        float4 b1 = *(const float4*)&bias[f0 + 4];
        float o[8];
        o[0] = fmaxf(acc[0] * si + b0.x, 0.f);
        o[1] = fmaxf(acc[1] * si + b0.y, 0.f);
        o[2] = fmaxf(acc[2] * si + b0.z, 0.f);
        o[3] = fmaxf(acc[3] * si + b0.w, 0.f);
        o[4] = fmaxf(acc[4] * si + b1.x, 0.f);
        o[5] = fmaxf(acc[5] * si + b1.y, 0.f);
        o[6] = fmaxf(acc[6] * si + b1.z, 0.f);
        o[7] = fmaxf(acc[7] * si + b1.w, 0.f);
        if constexpr (BF16OUT) {
            float so = inv_out[n];
            unsigned short u[8];
#pragma unroll
            for (int i = 0; i < 8; i++) u[i] = f2bf(o[i] * so);
            *(uint4*)&((__hip_bfloat16*)Xout)[(size_t)n * HID + f0] = *(uint4*)u;
        } else {
            float* Xf = (float*)Xout;
            *(float4*)&Xf[(size_t)n * HID + f0] = make_float4(o[0], o[1], o[2], o[3]);
            *(float4*)&Xf[(size_t)n * HID + f0 + 4] = make_float4(o[4], o[5], o[6], o[7]);
        }
    }
}

// ---------------- SumPooling: chunked segment-sum over sorted gid ----------------
__global__ __launch_bounds__(64) void pool_kernel(const float* __restrict__ X,
                                                  const int* __restrict__ gid,
                                                  float* __restrict__ emb) {
    int lane = threadIdx.x;
    int n0 = blockIdx.x * POOL_CHUNK;
    int n1 = min(n0 + POOL_CHUNK, N_NODES);
    if (n0 >= N_NODES) return;
    int g_cur = gid[n0];
    float ax = 0.f, ay = 0.f;
    for (int n = n0; n < n1; n++) {
        int g = gid[n];
        if (g != g_cur) {
            atomicAdd(&emb[g_cur * HID + lane * 2], ax);
            atomicAdd(&emb[g_cur * HID + lane * 2 + 1], ay);
            ax = 0.f; ay = 0.f;
            g_cur = g;
        }
        float2 v = *(const float2*)&X[(size_t)n * HID + lane * 2];
        ax += v.x;
        ay += v.y;
    }
    atomicAdd(&emb[g_cur * HID + lane * 2], ax);
    atomicAdd(&emb[g_cur * HID + lane * 2 + 1], ay);
}

// ---------------- fused BN-stats + fc1 + fc2 + log_softmax ----------------
// 128 blocks x 128 threads; each block redundantly computes BN stats (L2-hot 64 KB).
__global__ __launch_bounds__(128) void head_fused_kernel(const float* __restrict__ emb,
                                                         const float* __restrict__ gamma,
                                                         const float* __restrict__ beta,
                                                         const float* __restrict__ fc1_w,
                                                         const float* __restrict__ fc1_b,
                                                         const float* __restrict__ fc2_w,
                                                         const float* __restrict__ fc2_b,
                                                         float* __restrict__ out) {
    int r = blockIdx.x, f = threadIdx.x;
    float s = 0.f;
    for (int row = 0; row < N_GRAPHS; row++) s += emb[row * HID + f];
    float mu = s * (1.f / N_GRAPHS);
    float v = 0.f;
    for (int row = 0; row < N_GRAPHS; row++) {
        float d = emb[row * HID + f] - mu;
        v += d * d;
    }
    v *= (1.f / N_GRAPHS);
    float sc = gamma[f] * rsqrtf(v + BN_EPS);
    float sh = beta[f] - mu * sc;

    __shared__ float xr[HID];
    xr[f] = emb[r * HID + f] * sc + sh;
    __syncthreads();
    float acc = fc1_b[f];
    for (int k = 0; k < HID; k++) acc += xr[k] * fc1_w[k * HID + f];
    __shared__ float hr[HID];
    hr[f] = fmaxf(acc, 0.f);
    __syncthreads();

    __shared__ float logits[OUTC];
    __shared__ float mstat[2];
    if (f < OUTC) {
        float a = fc2_b[f];
        for (int k = 0; k < HID; k++) a += hr[k] * fc2_w[k * OUTC + f];
        logits[f] = a;
    }
    __syncthreads();
    if (f == 0) {
        float m = logits[0];
        for (int o = 1; o < OUTC; o++) m = fmaxf(m, logits[o]);
        float sum = 0.f;
        for (int o = 0; o < OUTC; o++) sum += expf(logits[o] - m);
        mstat[0] = m;
        mstat[1] = logf(sum);
    }
    __syncthreads();
    if (f < OUTC) out[r * OUTC + f] = logits[f] - mstat[0] - mstat[1];
}

extern "C" void kernel_launch(void* const* d_in, const int* in_sizes, int n_in,
                              void* d_out, int out_size, void* d_ws, size_t ws_size,
                              hipStream_t stream) {
    const float* n_feat = (const float*)d_in[0];
    const int*   src    = (const int*)d_in[1];
    const int*   dst    = (const int*)d_in[2];
    const int*   gid    = (const int*)d_in[3];
    const float* W1     = (const float*)d_in[4];
    const float* b1     = (const float*)d_in[5];
    const float* W2     = (const float*)d_in[6];
    const float* b2     = (const float*)d_in[7];
    const float* gamma  = (const float*)d_in[8];
    const float* beta   = (const float*)d_in[9];
    const float* fc1_w  = (const float*)d_in[10];
    const float* fc1_b  = (const float*)d_in[11];
    const float* fc2_w  = (const float*)d_in[12];
    const float* fc2_b  = (const float*)d_in[13];

    char* wsb = (char*)d_ws;
    size_t off = 0;
    auto alloc = [&](size_t bytes) -> void* {
        void* p = wsb + off;
        off += (bytes + 255) & ~(size_t)255;
        return p;
    };
    int*   cnt_out = (int*)alloc((size_t)N_NODES * 4);   // adjacent: one memset covers both
    int*   cnt_in  = (int*)alloc((size_t)N_NODES * 4);
    int*   cursor  = (int*)alloc((size_t)N_NODES * 4);
    int*   row_ptr = (int*)alloc((size_t)(N_NODES + 1) * 4);
    int*   e_src   = (int*)alloc((size_t)E_SRC_CAP * 4);
    float* inv_out = (float*)alloc((size_t)N_NODES * 4);
    float* inv_in  = (float*)alloc((size_t)N_NODES * 4);
    __hip_bfloat16* Y = (__hip_bfloat16*)alloc((size_t)(N_NODES + 1) * HID * 2);
    float* X       = (float*)alloc((size_t)N_NODES * HID * 4);       // layer-2 fp32 activations
    __hip_bfloat16* X1b = (__hip_bfloat16*)alloc((size_t)N_NODES * HID * 2);  // layer-1 bf16 pre-scaled
    unsigned short* Wp = (unsigned short*)alloc((size_t)2 * 32 * 64 * 8 * 2);  // 64 KB packed W1+W2
    int*   bsum    = (int*)alloc((size_t)SCAN_B * 4);

    float* emb_out = (float*)d_out;                // [128,128]
    float* lsm_out = emb_out + N_GRAPHS * HID;     // [128,10]

    // zero degree counters (cnt_out+cnt_in adjacent, 256B-aligned allocs) and emb output
    hipMemsetAsync(cnt_out, 0, (size_t)2 * ((N_NODES * 4 + 255) & ~255), stream);
    hipMemsetAsync(emb_out, 0, (size_t)N_GRAPHS * HID * 4, stream);

    deg_kernel<<<DEG_BLOCKS + 1, 1024, 0, stream>>>(src, dst, cnt_out, cnt_in, W1, W2, Wp);
    bsum_kernel<<<N_SCAN_BLOCKS, SCAN_B, 0, stream>>>(cnt_in, bsum);
    scan_write_kernel<<<N_SCAN_BLOCKS, SCAN_B, 0, stream>>>(cnt_out, cnt_in, bsum, row_ptr,
                                                            cursor, inv_out, inv_in, e_src);
    csr_fill_kernel<<<DEG_BLOCKS, 1024, 0, stream>>>(src, dst, cursor, e_src);

    // layer 1 (MFMA bf16): fp32 input w/ inv_out scale -> bf16 Y -> gather -> bf16 pre-scaled X1b
    matmul_kernel<<<(N_NODES + 64) / 64, 256, 0, stream>>>(n_feat, inv_out, Wp, Y);
    agg_kernel_t<true><<<(N_NODES + 3) / 4, 256, 0, stream>>>(Y, e_src, row_ptr, inv_in,
                                                              inv_out, b1, X1b);
    // layer 2: bf16 pre-scaled input -> bf16 Y -> gather -> fp32 X
    matmul_bf16_kernel<<<(N_NODES + 64) / 64, 256, 0, stream>>>(X1b, Wp + (size_t)32 * 64 * 8, Y);
    agg_kernel_t<false><<<(N_NODES + 3) / 4, 256, 0, stream>>>(Y, e_src, row_ptr, inv_in,
                                                               nullptr, b2, X);

    // pooling -> embedding output
    pool_kernel<<<N_POOL_BLOCKS, 64, 0, stream>>>(X, gid, emb_out);
    // fused head
    head_fused_kernel<<<N_GRAPHS, HID, 0, stream>>>(emb_out, gamma, beta, fc1_w, fc1_b,
                                                    fc2_w, fc2_b, lsm_out);
}

// Round 5
// 244.697 us; speedup vs baseline: 1.3547x; 1.3547x over previous
//
#include <hip/hip_runtime.h>
#include <hip/hip_bf16.h>
#include <math.h>

#define N_NODES 50000
#define N_EDGES 800000
#define HID 128
#define N_GRAPHS 128
#define OUTC 10
#define BN_EPS 1e-5f

#define SCAN_B 256
#define N_SCAN_BLOCKS ((N_NODES + SCAN_B - 1) / SCAN_B)  // 196

#define POOL_CHUNK 32
#define N_POOL_BLOCKS ((N_NODES + POOL_CHUNK - 1) / POOL_CHUNK)  // 1563

#define HB 80                 // histogram blocks per index array
#define HWORDS (N_NODES / 2)  // 25000 packed u32 words (2 x u16 bins)
#define HR_B 128              // hist_reduce block: 128 words = 256 nodes = one scan chunk
#define HR_BLOCKS ((HWORDS + HR_B - 1) / HR_B)  // 196 == N_SCAN_BLOCKS

#define EPAD 8                // CSR row padding (edges), multiple of 8 for guard-free inner loop
#define E_SRC_CAP (N_EDGES + N_NODES * EPAD)  // worst-case padded edge slots

#define LDA 136               // LDS row stride (ushorts): 272 B = 17*16B -> aligned b128, 2-way banks

#define MM_BLOCKS ((N_NODES + 64) / 64)  // 782, covers dummy row N_NODES

typedef short short8 __attribute__((ext_vector_type(8)));
typedef float floatx4 __attribute__((ext_vector_type(4)));

template <typename T, typename F>
__device__ inline T bitcast(F f) {
    union { F a; T b; } u;
    u.a = f;
    return u.b;
}

__device__ inline unsigned short f2bf(float x) {
    return __hip_bfloat16_raw(__float2bfloat16(x)).x;
}

// ---------------- LDS partial histograms (no global atomics) + W-pack tail block ----------
// blocks [0,HB): histogram src; [HB,2HB): histogram dst; block 2HB: pack W1/W2 B-fragments.
// Global atomics are NOT an option here: device-scope RMW crosses the non-coherent XCD L2s
// at fabric rate (~67 us measured for 1.6M atomics in round 3).
__global__ __launch_bounds__(1024) void hist_part_kernel(const int* __restrict__ src,
                                                         const int* __restrict__ dst,
                                                         unsigned int* __restrict__ part,
                                                         const float* __restrict__ W1,
                                                         const float* __restrict__ W2,
                                                         unsigned short* __restrict__ Wp) {
    if (blockIdx.x == 2 * HB) {
        // pack W into MFMA B-frag order: lane holds B[k=quad*8+j][n=lane&15], j in [0,8)
        for (int q = threadIdx.x; q < 4096; q += 1024) {  // 2 mats x 32 tiles x 64 lanes
            int wi = q >> 11;
            const float* __restrict__ W = wi ? W2 : W1;
            int t2 = q & 2047;
            int tile = t2 >> 6, lane = t2 & 63;
            int kc = tile >> 3, nt = tile & 7;
            int n = lane & 15, quad = lane >> 4;
            unsigned short v[8];
#pragma unroll
            for (int j = 0; j < 8; j++) {
                int k = kc * 32 + quad * 8 + j;
                v[j] = f2bf(W[k * HID + nt * 16 + n]);
            }
            *(uint4*)&Wp[(size_t)q * 8] = *(uint4*)v;
        }
        return;
    }
    __shared__ unsigned int h[HWORDS];  // 100 KB
    for (int i = threadIdx.x; i < HWORDS; i += 1024) h[i] = 0;
    __syncthreads();
    int half = (blockIdx.x >= HB) ? 1 : 0;
    const int* __restrict__ idx = half ? dst : src;
    int b = blockIdx.x - half * HB;
    for (int e = b * 1024 + threadIdx.x; e < N_EDGES; e += HB * 1024) {
        int v = idx[e];
        atomicAdd(&h[v >> 1], 1u << ((v & 1) << 4));  // LDS atomic, CU-local
    }
    __syncthreads();
    unsigned int* __restrict__ out = part + (size_t)blockIdx.x * HWORDS;
    for (int i = threadIdx.x; i < HWORDS; i += 1024) out[i] = h[i];
}

// Sum partials -> cnt_in / inv_out / inv_in; convert dst half of `part` in place to
// per-(block,node) exclusive prefixes; ALSO emit per-256-node-chunk padded sums (scan phase 1).
__global__ __launch_bounds__(HR_B) void hist_reduce_kernel(unsigned int* __restrict__ part,
                                                           int* __restrict__ cnt_in,
                                                           float* __restrict__ inv_out,
                                                           float* __restrict__ inv_in,
                                                           int* __restrict__ bsum) {
    int w = blockIdx.x * HR_B + threadIdx.x;
    int padsum = 0;
    if (w < HWORDS) {
        unsigned int s = 0, d = 0;
        for (int b = 0; b < HB; b++) {
            s += part[(size_t)b * HWORDS + w];
            unsigned int c = part[(size_t)(b + HB) * HWORDS + w];
            part[(size_t)(b + HB) * HWORDS + w] = d;  // exclusive prefix over blocks
            d += c;
        }
        int i0 = w * 2, i1 = i0 + 1;
        int so0 = (int)(s & 0xFFFFu), so1 = (int)(s >> 16);
        int di0 = (int)(d & 0xFFFFu), di1 = (int)(d >> 16);
        cnt_in[i0] = di0;
        cnt_in[i1] = di1;
        inv_out[i0] = rsqrtf(fmaxf((float)so0, 1.0f));
        inv_out[i1] = rsqrtf(fmaxf((float)so1, 1.0f));
        inv_in[i0] = rsqrtf(fmaxf((float)di0, 1.0f));
        inv_in[i1] = rsqrtf(fmaxf((float)di1, 1.0f));
        padsum = ((di0 + EPAD - 1) & ~(EPAD - 1)) + ((di1 + EPAD - 1) & ~(EPAD - 1));
    }
    __shared__ int red[HR_B];
    red[threadIdx.x] = padsum;
    __syncthreads();
    for (int o = HR_B / 2; o > 0; o >>= 1) {
        if (threadIdx.x < o) red[threadIdx.x] += red[threadIdx.x + o];
        __syncthreads();
    }
    if (threadIdx.x == 0) bsum[blockIdx.x] = red[0];
}

// ================= MFMA matmul tail (shared by both stagings) =================
__device__ inline void mm_tail(const unsigned short* __restrict__ xs,
                               const unsigned short* __restrict__ Wp,
                               __hip_bfloat16* __restrict__ Y, int row0) {
    int tid = threadIdx.x;
    int wave = tid >> 6, lane = tid & 63;
    int m = lane & 15, quad = lane >> 4;
    int rowl = wave * 16;

    short8 a[4];
#pragma unroll
    for (int kc = 0; kc < 4; kc++)
        a[kc] = bitcast<short8>(*(const uint4*)&xs[(rowl + m) * LDA + kc * 32 + quad * 8]);

    floatx4 acc[8];
#pragma unroll
    for (int nt = 0; nt < 8; nt++) acc[nt] = (floatx4){0.f, 0.f, 0.f, 0.f};

#pragma unroll
    for (int nt = 0; nt < 8; nt++) {
#pragma unroll
        for (int kc = 0; kc < 4; kc++) {
            short8 bfr = bitcast<short8>(
                *(const uint4*)&Wp[((size_t)(kc * 8 + nt) * 64 + lane) * 8]);
            acc[nt] = __builtin_amdgcn_mfma_f32_16x16x32_bf16(a[kc], bfr, acc[nt], 0, 0, 0);
        }
    }

    // C/D layout: col = lane&15, row = quad*4 + reg  [verified m89]
#pragma unroll
    for (int nt = 0; nt < 8; nt++) {
#pragma unroll
        for (int i = 0; i < 4; i++) {
            int rg = row0 + rowl + quad * 4 + i;
            if (rg < N_NODES + 1) {
                Y[(size_t)rg * HID + nt * 16 + m] = __float2bfloat16(acc[nt][i]);
            }
        }
    }
}

// ---------------- fused: scan/row_ptr write  ||  matmul1  ||  emb zero ----------------
// All three depend only on hist_reduce (+hist_part's Wp). Block-range split, no sync needed:
//   [0, NSB)           : bsum scan (redundant per block) + row_ptr + pad-slot fill
//   [NSB, NSB+MM)      : layer-1 MFMA matmul Y = bf16((inv_out*X) @ W1)
//   NSB+MM             : zero emb accumulator
// NOTE: Y must NOT alias the partials buffer — csr_fill still reads the dst-half prefixes
// after this kernel (round-4 crash root cause).
__global__ __launch_bounds__(256) void scanmm1_kernel(const int* __restrict__ cnt,
                                                      const int* __restrict__ bsum,
                                                      int* __restrict__ row_ptr,
                                                      int* __restrict__ edge_src,
                                                      const float* __restrict__ X,
                                                      const float* __restrict__ scale,
                                                      const unsigned short* __restrict__ Wp,
                                                      __hip_bfloat16* __restrict__ Y,
                                                      float* __restrict__ emb) {
    __shared__ unsigned short xs[64 * LDA];  // 17.4 KB; scan aliases first 2 KB
    int t = threadIdx.x;
    int b = blockIdx.x;

    if (b >= N_SCAN_BLOCKS) {
        if (b == N_SCAN_BLOCKS + MM_BLOCKS) {  // emb zero
            for (int i = t; i < N_GRAPHS * HID; i += 256) emb[i] = 0.f;
            return;
        }
        // ---- matmul1: stage 64x128 fp32 -> scaled bf16 LDS (coalesced float4 loads) ----
        int row0 = (b - N_SCAN_BLOCKS) * 64;
        for (int j = 0; j < 8; j++) {
            int idx4 = j * 256 + t;
            int r = idx4 >> 5;
            int col = (idx4 & 31) * 4;
            int rg = row0 + r;
            float4 v = make_float4(0.f, 0.f, 0.f, 0.f);
            if (rg < N_NODES) {
                v = *(const float4*)&X[(size_t)rg * HID + col];
                float sc = scale[rg];
                v.x *= sc; v.y *= sc; v.z *= sc; v.w *= sc;
            }
            unsigned short o[4];
            o[0] = f2bf(v.x); o[1] = f2bf(v.y); o[2] = f2bf(v.z); o[3] = f2bf(v.w);
            *(ushort4*)&xs[r * LDA + col] = *(ushort4*)o;
        }
        __syncthreads();
        mm_tail(xs, Wp, Y, row0);
        return;
    }

    // ---- scan: per-block redundant bsum scan + node scan + row_ptr/pad write ----
    int* sb = (int*)xs;          // [0,256)
    int* part = (int*)xs + 256;  // [256,512)
    sb[t] = (t < N_SCAN_BLOCKS) ? bsum[t] : 0;
    __syncthreads();
    for (int off = 1; off < SCAN_B; off <<= 1) {
        int u = (t >= off) ? sb[t - off] : 0;
        __syncthreads();
        sb[t] += u;
        __syncthreads();
    }
    int boff = (b == 0) ? 0 : sb[b - 1];  // exclusive chunk offset

    int i = b * SCAN_B + t;
    int raw = (i < N_NODES) ? cnt[i] : 0;
    int v = (raw + EPAD - 1) & ~(EPAD - 1);
    part[t] = v;
    __syncthreads();
    for (int off = 1; off < SCAN_B; off <<= 1) {
        int u = (t >= off) ? part[t - off] : 0;
        __syncthreads();
        part[t] += u;
        __syncthreads();
    }
    if (i < N_NODES) {
        int ex = part[t] - v + boff;
        row_ptr[i] = ex;
        for (int p = ex + raw; p < ex + v; p++) edge_src[p] = N_NODES;  // pad slots
        if (i == N_NODES - 1) row_ptr[N_NODES] = ex + v;  // padded total
    }
}

// ---------------- CSR fill, atomic-free (disjoint from pad slots) ----------------
__global__ __launch_bounds__(1024) void csr_fill_kernel(const int* __restrict__ src,
                                                        const int* __restrict__ dst,
                                                        const unsigned int* __restrict__ part,
                                                        const int* __restrict__ row_ptr,
                                                        int* __restrict__ edge_src) {
    __shared__ unsigned int loc[HWORDS];  // 100 KB: packed u16 running intra-bucket slots
    int b = blockIdx.x;
    const unsigned int* __restrict__ off = part + (size_t)(b + HB) * HWORDS;
    for (int i = threadIdx.x; i < HWORDS; i += 1024) loc[i] = off[i];
    __syncthreads();
    for (int e = b * 1024 + threadIdx.x; e < N_EDGES; e += HB * 1024) {
        int d = dst[e];
        unsigned int old = atomicAdd(&loc[d >> 1], 1u << ((d & 1) << 4));  // LDS atomic
        int local = (d & 1) ? (int)(old >> 16) : (int)(old & 0xFFFFu);
        edge_src[row_ptr[d] + local] = src[e];  // plain scattered store
    }
}

// bf16 pre-scaled input (layer 2): staging is a straight vectorized copy
__global__ __launch_bounds__(256) void matmul_bf16_kernel(const __hip_bfloat16* __restrict__ Xb,
                                                          const unsigned short* __restrict__ Wp,
                                                          __hip_bfloat16* __restrict__ Y) {
    __shared__ unsigned short xs[64 * LDA];
    int tid = threadIdx.x;
    int row0 = blockIdx.x * 64;
    for (int j = 0; j < 4; j++) {
        int idx8 = j * 256 + tid;  // 8-bf16 chunks: 16 per row
        int r = idx8 >> 4;
        int c = (idx8 & 15) * 8;
        int rg = row0 + r;
        uint4 v = make_uint4(0u, 0u, 0u, 0u);
        if (rg < N_NODES) v = *(const uint4*)&Xb[(size_t)rg * HID + c];
        *(uint4*)&xs[r * LDA + c] = v;
    }
    __syncthreads();
    mm_tail(xs, Wp, Y, row0);
}

// ================= CSR gather-accumulate =================
// BF16OUT: store bf16(inv_out[n] * relu(acc*inv_in + b)) — pre-scaled for next matmul.
// else:    store fp32 relu(acc*inv_in + b) for pooling.
// Inner loop unrolled to 4 in-flight 16B gathers (latency-bound on scattered L2/L3 reads).
// Accumulation order identical to the 2-gather version (bitwise-same results).
#define ACC8(u)                                                                              \
    acc[0] += __uint_as_float(u.x << 16); acc[1] += __uint_as_float(u.x & 0xFFFF0000u);      \
    acc[2] += __uint_as_float(u.y << 16); acc[3] += __uint_as_float(u.y & 0xFFFF0000u);      \
    acc[4] += __uint_as_float(u.z << 16); acc[5] += __uint_as_float(u.z & 0xFFFF0000u);      \
    acc[6] += __uint_as_float(u.w << 16); acc[7] += __uint_as_float(u.w & 0xFFFF0000u);

template <bool BF16OUT>
__global__ __launch_bounds__(256) void agg_kernel_t(const __hip_bfloat16* __restrict__ Y,
                                                    const int* __restrict__ edge_src,
                                                    const int* __restrict__ row_ptr,
                                                    const float* __restrict__ inv_in,
                                                    const float* __restrict__ inv_out,
                                                    const float* __restrict__ bias,
                                                    void* __restrict__ Xout) {
    const uint4* __restrict__ Yq = (const uint4*)Y;  // 8 bf16 per uint4
    int wave = threadIdx.x >> 6;
    int lane = threadIdx.x & 63;
    int n = blockIdx.x * 4 + wave;
    if (n >= N_NODES) return;
    int beg = row_ptr[n], end = row_ptr[n + 1];  // length multiple of 8
    int esub = lane >> 4;   // which of 4 concurrent edges
    int f16  = lane & 15;   // feature quad: feats f16*8 .. f16*8+7
    float acc[8] = {};
    for (int base = beg; base < end; base += 64) {
        int mm = min(64, end - base);  // multiple of 8
        int idx = (lane < mm) ? edge_src[base + lane] : N_NODES;
        int j = 0;
        for (; j + 16 <= mm; j += 16) {  // 16 edges: 4 independent gathers in flight
            int s0 = __shfl(idx, j + esub);
            int s1 = __shfl(idx, j + 4 + esub);
            int s2 = __shfl(idx, j + 8 + esub);
            int s3 = __shfl(idx, j + 12 + esub);
            uint4 u0 = Yq[s0 * (HID / 8) + f16];
            uint4 u1 = Yq[s1 * (HID / 8) + f16];
            uint4 u2 = Yq[s2 * (HID / 8) + f16];
            uint4 u3 = Yq[s3 * (HID / 8) + f16];
            ACC8(u0); ACC8(u1); ACC8(u2); ACC8(u3);
        }
        if (j < mm) {  // exactly 8 remaining (mm % 8 == 0)
            int s0 = __shfl(idx, j + esub);
            int s1 = __shfl(idx, j + 4 + esub);
            uint4 u0 = Yq[s0 * (HID / 8) + f16];
            uint4 u1 = Yq[s1 * (HID / 8) + f16];
            ACC8(u0); ACC8(u1);
        }
    }
#pragma unroll
    for (int i = 0; i < 8; i++) {
        acc[i] += __shfl_xor(acc[i], 16);
        acc[i] += __shfl_xor(acc[i], 32);
    }
    if (lane < 16) {
        float si = inv_in[n];
        int f0 = f16 * 8;
        float4 b0 = *(const float4*)&bias[f0];
        float4 b1 = *(const float4*)&bias[f0 + 4];
        float o[8];
        o[0] = fmaxf(acc[0] * si + b0.x, 0.f);
        o[1] = fmaxf(acc[1] * si + b0.y, 0.f);
        o[2] = fmaxf(acc[2] * si + b0.z, 0.f);
        o[3] = fmaxf(acc[3] * si + b0.w, 0.f);
        o[4] = fmaxf(acc[4] * si + b1.x, 0.f);
        o[5] = fmaxf(acc[5] * si + b1.y, 0.f);
        o[6] = fmaxf(acc[6] * si + b1.z, 0.f);
        o[7] = fmaxf(acc[7] * si + b1.w, 0.f);
        if constexpr (BF16OUT) {
            float so = inv_out[n];
            unsigned short u[8];
#pragma unroll
            for (int i = 0; i < 8; i++) u[i] = f2bf(o[i] * so);
            *(uint4*)&((__hip_bfloat16*)Xout)[(size_t)n * HID + f0] = *(uint4*)u;
        } else {
            float* Xf = (float*)Xout;
            *(float4*)&Xf[(size_t)n * HID + f0] = make_float4(o[0], o[1], o[2], o[3]);
            *(float4*)&Xf[(size_t)n * HID + f0 + 4] = make_float4(o[4], o[5], o[6], o[7]);
        }
    }
}

// ---------------- SumPooling: chunked segment-sum over sorted gid ----------------
__global__ __launch_bounds__(64) void pool_kernel(const float* __restrict__ X,
                                                  const int* __restrict__ gid,
                                                  float* __restrict__ emb) {
    int lane = threadIdx.x;
    int n0 = blockIdx.x * POOL_CHUNK;
    int n1 = min(n0 + POOL_CHUNK, N_NODES);
    if (n0 >= N_NODES) return;
    int g_cur = gid[n0];
    float ax = 0.f, ay = 0.f;
    for (int n = n0; n < n1; n++) {
        int g = gid[n];
        if (g != g_cur) {
            atomicAdd(&emb[g_cur * HID + lane * 2], ax);
            atomicAdd(&emb[g_cur * HID + lane * 2 + 1], ay);
            ax = 0.f; ay = 0.f;
            g_cur = g;
        }
        float2 v = *(const float2*)&X[(size_t)n * HID + lane * 2];
        ax += v.x;
        ay += v.y;
    }
    atomicAdd(&emb[g_cur * HID + lane * 2], ax);
    atomicAdd(&emb[g_cur * HID + lane * 2 + 1], ay);
}

// ---------------- fused BN-stats + fc1 + fc2 + log_softmax ----------------
// 128 blocks x 128 threads; each block redundantly computes BN stats (L2-hot 64 KB).
__global__ __launch_bounds__(128) void head_fused_kernel(const float* __restrict__ emb,
                                                         const float* __restrict__ gamma,
                                                         const float* __restrict__ beta,
                                                         const float* __restrict__ fc1_w,
                                                         const float* __restrict__ fc1_b,
                                                         const float* __restrict__ fc2_w,
                                                         const float* __restrict__ fc2_b,
                                                         float* __restrict__ out) {
    int r = blockIdx.x, f = threadIdx.x;
    float s = 0.f;
    for (int row = 0; row < N_GRAPHS; row++) s += emb[row * HID + f];
    float mu = s * (1.f / N_GRAPHS);
    float v = 0.f;
    for (int row = 0; row < N_GRAPHS; row++) {
        float d = emb[row * HID + f] - mu;
        v += d * d;
    }
    v *= (1.f / N_GRAPHS);
    float sc = gamma[f] * rsqrtf(v + BN_EPS);
    float sh = beta[f] - mu * sc;

    __shared__ float xr[HID];
    xr[f] = emb[r * HID + f] * sc + sh;
    __syncthreads();
    float acc = fc1_b[f];
    for (int k = 0; k < HID; k++) acc += xr[k] * fc1_w[k * HID + f];
    __shared__ float hr[HID];
    hr[f] = fmaxf(acc, 0.f);
    __syncthreads();

    __shared__ float logits[OUTC];
    __shared__ float mstat[2];
    if (f < OUTC) {
        float a = fc2_b[f];
        for (int k = 0; k < HID; k++) a += hr[k] * fc2_w[k * OUTC + f];
        logits[f] = a;
    }
    __syncthreads();
    if (f == 0) {
        float m = logits[0];
        for (int o = 1; o < OUTC; o++) m = fmaxf(m, logits[o]);
        float sum = 0.f;
        for (int o = 0; o < OUTC; o++) sum += expf(logits[o] - m);
        mstat[0] = m;
        mstat[1] = logf(sum);
    }
    __syncthreads();
    if (f < OUTC) out[r * OUTC + f] = logits[f] - mstat[0] - mstat[1];
}

extern "C" void kernel_launch(void* const* d_in, const int* in_sizes, int n_in,
                              void* d_out, int out_size, void* d_ws, size_t ws_size,
                              hipStream_t stream) {
    const float* n_feat = (const float*)d_in[0];
    const int*   src    = (const int*)d_in[1];
    const int*   dst    = (const int*)d_in[2];
    const int*   gid    = (const int*)d_in[3];
    const float* W1     = (const float*)d_in[4];
    const float* b1     = (const float*)d_in[5];
    const float* W2     = (const float*)d_in[6];
    const float* b2     = (const float*)d_in[7];
    const float* gamma  = (const float*)d_in[8];
    const float* beta   = (const float*)d_in[9];
    const float* fc1_w  = (const float*)d_in[10];
    const float* fc1_b  = (const float*)d_in[11];
    const float* fc2_w  = (const float*)d_in[12];
    const float* fc2_b  = (const float*)d_in[13];

    char* wsb = (char*)d_ws;
    size_t off = 0;
    auto alloc = [&](size_t bytes) -> void* {
        void* p = wsb + off;
        off += (bytes + 255) & ~(size_t)255;
        return p;
    };
    int*   cnt_in  = (int*)alloc((size_t)N_NODES * 4);
    int*   row_ptr = (int*)alloc((size_t)(N_NODES + 1) * 4);
    int*   e_src   = (int*)alloc((size_t)E_SRC_CAP * 4);
    float* inv_out = (float*)alloc((size_t)N_NODES * 4);
    float* inv_in  = (float*)alloc((size_t)N_NODES * 4);
    // partials buffer: 2*HB*HWORDS u32 = 16 MB (NOT aliased with Y — round-4 crash fix)
    unsigned int* part = (unsigned int*)alloc((size_t)2 * HB * HWORDS * 4);
    __hip_bfloat16* Y  = (__hip_bfloat16*)alloc((size_t)(N_NODES + 1) * HID * 2);  // 12.8 MB
    float* X       = (float*)alloc((size_t)N_NODES * HID * 4);       // layer-2 fp32 activations
    __hip_bfloat16* X1b = (__hip_bfloat16*)alloc((size_t)N_NODES * HID * 2);  // layer-1 bf16 pre-scaled
    unsigned short* Wp = (unsigned short*)alloc((size_t)2 * 32 * 64 * 8 * 2);  // 64 KB packed W1+W2
    int*   bsum    = (int*)alloc((size_t)SCAN_B * 4);

    float* emb_out = (float*)d_out;                // [128,128]
    float* lsm_out = emb_out + N_GRAPHS * HID;     // [128,10]

    hist_part_kernel<<<2 * HB + 1, 1024, 0, stream>>>(src, dst, part, W1, W2, Wp);
    hist_reduce_kernel<<<HR_BLOCKS, HR_B, 0, stream>>>(part, cnt_in, inv_out, inv_in, bsum);
    // fused: scan/row_ptr || matmul1 || emb zero (all depend only on hist_reduce/hist_part)
    scanmm1_kernel<<<N_SCAN_BLOCKS + MM_BLOCKS + 1, 256, 0, stream>>>(
        cnt_in, bsum, row_ptr, e_src, n_feat, inv_out, Wp, Y, emb_out);
    csr_fill_kernel<<<HB, 1024, 0, stream>>>(src, dst, part, row_ptr, e_src);

    // layer 1 gather -> bf16 pre-scaled X1b
    agg_kernel_t<true><<<(N_NODES + 3) / 4, 256, 0, stream>>>(Y, e_src, row_ptr, inv_in,
                                                              inv_out, b1, X1b);
    // layer 2: bf16 pre-scaled input -> bf16 Y -> gather -> fp32 X
    matmul_bf16_kernel<<<MM_BLOCKS, 256, 0, stream>>>(X1b, Wp + (size_t)32 * 64 * 8, Y);
    agg_kernel_t<false><<<(N_NODES + 3) / 4, 256, 0, stream>>>(Y, e_src, row_ptr, inv_in,
                                                               nullptr, b2, X);

    // pooling -> embedding output
    pool_kernel<<<N_POOL_BLOCKS, 64, 0, stream>>>(X, gid, emb_out);
    // fused head
    head_fused_kernel<<<N_GRAPHS, HID, 0, stream>>>(emb_out, gamma, beta, fc1_w, fc1_b,
                                                    fc2_w, fc2_b, lsm_out);
}